// Round 10
// baseline (4578.506 us; speedup 1.0000x reference)
//
#include <hip/hip_runtime.h>
#include <hip/hip_bf16.h>

// T=512, B=64, D=1024, H=1024, 4H=4096
// Pass 0: pack Wi -> split-bf16 (hi/lo) in MFMA B-fragment order (ws, 16MB)
// Pass 1: G2 = x @ Wi + b via split-bf16 MFMA, scan-native layout:
//         G2[((step*256 + wg)*4 + gate)*256 + b*4 + u]  (bf16)
// Pass 2: cooperative scan, 256 WGs x 4 hidden units, MFMA z = G + h @ Wh.
//         h publish: sc1 stores -> IF$.  h read:
//           RING path (ws permitting): 513-slot no-reuse ring, PLAIN cached
//           loads — reader L2 never saw the address this launch, so the
//           demand miss pulls the fresh IF$ copy; 32 WGs/XCD share it via L2
//           (32x dedup of the IF$ broadcast, no fences).
//           Fallback: round-9 verified hp0/hp1 + sc1 atomic reads.
//         Barrier: round-5 form (flags 128B apart, all-thread poll).

typedef __attribute__((ext_vector_type(8))) short bf16x8;
typedef __attribute__((ext_vector_type(8))) unsigned short ushx8;
typedef __attribute__((ext_vector_type(4))) unsigned short ushx4;
typedef __attribute__((ext_vector_type(4))) float f32x4;
typedef __attribute__((ext_vector_type(2))) unsigned long long u64x2;

static __device__ __forceinline__ unsigned short f2bf(float x) {
    __hip_bfloat16 h = __float2bfloat16(x);
    return __builtin_bit_cast(unsigned short, h);
}
static __device__ __forceinline__ float bf2f(unsigned short u) {
    __hip_bfloat16 h = __builtin_bit_cast(__hip_bfloat16, u);
    return __bfloat162float(h);
}

// coherent (agent-scope, L2-bypassing) 16B load as 2 x u64 relaxed atomics
static __device__ __forceinline__ bf16x8 ld_h16(const unsigned long long* p) {
    unsigned long long a = __hip_atomic_load(p,     __ATOMIC_RELAXED, __HIP_MEMORY_SCOPE_AGENT);
    unsigned long long b = __hip_atomic_load(p + 1, __ATOMIC_RELAXED, __HIP_MEMORY_SCOPE_AGENT);
    u64x2 v; v.x = a; v.y = b;
    return __builtin_bit_cast(bf16x8, v);
}

static __device__ __forceinline__ void gl_lds16(const void* g, void* l) {
    __builtin_amdgcn_global_load_lds(
        (const __attribute__((address_space(1))) unsigned int*)g,
        (__attribute__((address_space(3))) unsigned int*)l, 16, 0, 0);
}

static __device__ __forceinline__ float sigm_fast(float x) {
    return 1.f / (1.f + __expf(-x));
}
static __device__ __forceinline__ float tanh_fast(float x) {
    float e = __expf(2.f * x);
    return 1.f - 2.f / (e + 1.f);
}

// ---------------------------------------------------------------------------
// Pass 0: pack Wi[1024][4096] f32 -> WiHi/WiLo bf16 in B-fragment order.
// ---------------------------------------------------------------------------
__global__ __launch_bounds__(256)
void wi_pack(const float* __restrict__ Wi, unsigned short* __restrict__ WiHi,
             unsigned short* __restrict__ WiLo)
{
    const int bid = blockIdx.x;            // 1024 = tn(32) x kb(32)
    const int tn = bid >> 5, kb = bid & 31;
    const int t = threadIdx.x;
    const int c = t & 127, ko = t >> 7;
    const float* src = Wi + (size_t)(kb * 32 + ko * 16) * 4096 + tn * 128 + c;
    const size_t dbase = ((size_t)(tn * 32 + kb)) * 4096 + c * 8;
#pragma unroll
    for (int o = 0; o < 2; ++o) {
        ushx8 hv, lv;
#pragma unroll
        for (int q = 0; q < 8; ++q) {
            float v = src[(size_t)(o * 8 + q) * 4096];
            unsigned short h = f2bf(v);
            hv[q] = h; lv[q] = f2bf(v - bf2f(h));
        }
        int kq = ko * 2 + o;
        *(ushx8*)(WiHi + dbase + kq * 1024) = hv;
        *(ushx8*)(WiLo + dbase + kq * 1024) = lv;
    }
}

// ---------------------------------------------------------------------------
// Pass 1: G2 = x @ Wi + bias, split-bf16 MFMA, 128x128 tile, BK=32, 4 waves.
// ---------------------------------------------------------------------------
__global__ __launch_bounds__(256)
void xwi_gemm_mfma(const float* __restrict__ x,
                   const unsigned short* __restrict__ WiHi,
                   const unsigned short* __restrict__ WiLo,
                   const float* __restrict__ bias,
                   unsigned short* __restrict__ G2)
{
    __shared__ __align__(16) unsigned short AHi[4096], ALo[4096];
    __shared__ __align__(16) unsigned short BHi[4096], BLo[4096];
    const int bid = blockIdx.x;
    const int bm = bid >> 5, bn = bid & 31;
    const int m0 = bm << 7, n0 = bn << 7;
    const int t = threadIdx.x;
    const int w = t >> 6, l = t & 63, lq = l >> 4, lc = l & 15;
    const int wm = w >> 1, wn = w & 1;

    f32x4 acc[4][4] = {};
    const int row = t >> 1, kh = t & 1;
    const float* xrow = x + (size_t)(m0 + row) * 1024 + kh * 16;
    const unsigned short* bHsl = WiHi + (size_t)(bn * 32) * 4096;
    const unsigned short* bLsl = WiLo + (size_t)(bn * 32) * 4096;

    for (int kb = 0; kb < 32; ++kb) {
        float4 f0 = *(const float4*)(xrow + kb * 32 + 0);
        float4 f1 = *(const float4*)(xrow + kb * 32 + 4);
        float4 f2 = *(const float4*)(xrow + kb * 32 + 8);
        float4 f3 = *(const float4*)(xrow + kb * 32 + 12);
        float fs[16] = {f0.x, f0.y, f0.z, f0.w, f1.x, f1.y, f1.z, f1.w,
                        f2.x, f2.y, f2.z, f2.w, f3.x, f3.y, f3.z, f3.w};
#pragma unroll
        for (int o = 0; o < 2; ++o) {
            ushx8 hv, lv;
#pragma unroll
            for (int q = 0; q < 8; ++q) {
                float v = fs[o * 8 + q];
                unsigned short h = f2bf(v);
                hv[q] = h; lv[q] = f2bf(v - bf2f(h));
            }
            int kq = kh * 2 + o;
            *(ushx8*)&AHi[kq * 1024 + row * 8] = hv;
            *(ushx8*)&ALo[kq * 1024 + row * 8] = lv;
        }
        {
            const unsigned short* sH = bHsl + (size_t)kb * 4096;
            const unsigned short* sL = bLsl + (size_t)kb * 4096;
            gl_lds16(sH + (size_t)(w * 128 + l) * 8,      &BHi[(w * 128) * 8]);
            gl_lds16(sH + (size_t)(w * 128 + 64 + l) * 8, &BHi[(w * 128 + 64) * 8]);
            gl_lds16(sL + (size_t)(w * 128 + l) * 8,      &BLo[(w * 128) * 8]);
            gl_lds16(sL + (size_t)(w * 128 + 64 + l) * 8, &BLo[(w * 128 + 64) * 8]);
        }
        __syncthreads();

        bf16x8 xh[4], xl[4], wh_[4], wl_[4];
#pragma unroll
        for (int a = 0; a < 4; ++a) {
            int off = lq * 1024 + (wm * 64 + a * 16 + lc) * 8;
            xh[a] = *(const bf16x8*)&AHi[off];
            xl[a] = *(const bf16x8*)&ALo[off];
        }
#pragma unroll
        for (int b = 0; b < 4; ++b) {
            int off = lq * 1024 + (wn * 64 + b * 16 + lc) * 8;
            wh_[b] = *(const bf16x8*)&BHi[off];
            wl_[b] = *(const bf16x8*)&BLo[off];
        }
#pragma unroll
        for (int a = 0; a < 4; ++a)
#pragma unroll
            for (int b = 0; b < 4; ++b) {
                acc[a][b] = __builtin_amdgcn_mfma_f32_16x16x32_bf16(wh_[b], xh[a], acc[a][b], 0, 0, 0);
                acc[a][b] = __builtin_amdgcn_mfma_f32_16x16x32_bf16(wl_[b], xh[a], acc[a][b], 0, 0, 0);
                acc[a][b] = __builtin_amdgcn_mfma_f32_16x16x32_bf16(wh_[b], xl[a], acc[a][b], 0, 0, 0);
            }
        __syncthreads();
    }

    float bv[4][4];
#pragma unroll
    for (int b = 0; b < 4; ++b)
#pragma unroll
        for (int r = 0; r < 4; ++r)
            bv[b][r] = bias[n0 + wn * 64 + b * 16 + lq * 4 + r];
#pragma unroll
    for (int a = 0; a < 4; ++a) {
        int m = m0 + wm * 64 + a * 16 + lc;
        int step = m >> 6, b_el = m & 63;
#pragma unroll
        for (int b = 0; b < 4; ++b) {
            int j_abs = n0 + wn * 64 + b * 16 + lq * 4;
            int gate = j_abs >> 10;
            int wg_t = (j_abs & 1023) >> 2;
            ushx4 sv;
#pragma unroll
            for (int r = 0; r < 4; ++r) sv[r] = f2bf(acc[a][b][r] + bv[b][r]);
            *(ushx4*)(G2 + (((size_t)(step * 256 + wg_t) * 4 + gate) * 256 + b_el * 4)) = sv;
        }
    }
}

// ---------------------------------------------------------------------------
// Pass 2: cooperative MFMA scan. 256 WGs x 256 threads (4 waves), 4 units/WG.
// RING=true : 513-slot h ring, plain cached reads (L2-dedup'd broadcast).
// RING=false: round-9 verified 2-slot + sc1 atomic reads.
// ---------------------------------------------------------------------------
template <bool RING>
__global__ __launch_bounds__(256, 1)
void lstm_scan_mfma(const unsigned short* __restrict__ G2,
                    const float* __restrict__ Wh,
                    const float* __restrict__ h0, const float* __restrict__ c0,
                    float* __restrict__ out,
                    unsigned int* hbase,
                    unsigned int* __restrict__ flags)
{
    __shared__ __align__(16) unsigned short WhHiS[16384];  // 32 KB
    __shared__ __align__(16) unsigned short WhLoS[16384];  // 32 KB
    __shared__ float zS[64 * 20];

    const int t  = threadIdx.x;
    const int wg = blockIdx.x;           // 0..255
    const int w  = t >> 6;
    const int l  = t & 63;
    const int lq = l >> 4, lc = l & 15;

    // Wh slice -> LDS (once): 16 z-cols, hi/lo split, B-fragment order
    for (int idx = t; idx < 16384; idx += 256) {
        int k = idx >> 4, c = idx & 15;
        int gcol = (c >> 2) * 1024 + wg * 4 + (c & 3);
        float wv = Wh[(size_t)k * 4096 + gcol];
        unsigned short hi = f2bf(wv);
        unsigned short lo = f2bf(wv - bf2f(hi));
        int pos = (((k >> 5) * 64) + (((k >> 3) & 3) * 16 + c)) * 8 + (k & 7);
        WhHiS[pos] = hi; WhLoS[pos] = lo;
    }

    // init h slot 0 from h0 (bf16 hi only, sc1 -> IF$)
    {
        int idx = wg * 256 + t;
        if (idx < 32768) {
            int b = idx >> 9, k = (idx & 511) * 2;
            unsigned short h0s = f2bf(h0[b * 1024 + k]);
            unsigned short h1s = f2bf(h0[b * 1024 + k + 1]);
            int p32 = ((k >> 3) * 64 + b) * 4 + ((k & 7) >> 1);
            __hip_atomic_store(hbase + p32, (unsigned int)h0s | ((unsigned int)h1s << 16),
                               __ATOMIC_RELAXED, __HIP_MEMORY_SCOPE_AGENT);
        }
    }

    const int b_el = t >> 2, u_el = t & 3;
    const int j = wg * 4 + u_el;
    float c_state = c0[b_el * 1024 + j];

    // initial barrier (round-5 form)
    {
        asm volatile("s_waitcnt vmcnt(0)" ::: "memory");
        __syncthreads();
        if (t == 0)
            __hip_atomic_store(&flags[wg * 32], 1u, __ATOMIC_RELAXED,
                               __HIP_MEMORY_SCOPE_AGENT);
        while (__hip_atomic_load(&flags[t * 32], __ATOMIC_RELAXED,
                                 __HIP_MEMORY_SCOPE_AGENT) < 1u) {}
        __syncthreads();
        asm volatile("" ::: "memory");
    }

    const int arow = (w << 4) + lc;
    for (int step = 0; step < 512; ++step) {
        const unsigned short* hS = (const unsigned short*)
            (hbase + (size_t)(RING ? step : (step & 1)) * 32768);
        unsigned int* nH = hbase + (size_t)(RING ? (step + 1) : ((step + 1) & 1)) * 32768;

        // G prefetch: contiguous 2KB/WG panel, 4 x 2B per thread (dense)
        size_t pb = ((size_t)(step * 256 + wg) * 4) * 256 + t;
        unsigned short gvi = G2[pb];
        unsigned short gvf = G2[pb + 256];
        unsigned short gvg = G2[pb + 512];
        unsigned short gvo = G2[pb + 768];

        f32x4 acc0 = {0.f, 0.f, 0.f, 0.f};
        f32x4 acc2 = {0.f, 0.f, 0.f, 0.f};

        // software-pipelined K loop: 4 groups of 8 kb, double-buffered regs
        bf16x8 ah[2][8];
#pragma unroll
        for (int i = 0; i < 8; ++i) {
            int apos = ((i * 4 + lq) * 64 + arow) * 8;
            if (RING) ah[0][i] = *(const bf16x8*)(hS + apos);
            else      ah[0][i] = ld_h16((const unsigned long long*)hS + (apos >> 2));
        }
#pragma unroll
        for (int g4 = 0; g4 < 4; ++g4) {
            if (g4 < 3) {
#pragma unroll
                for (int i = 0; i < 8; ++i) {
                    int kb = (g4 + 1) * 8 + i;
                    int apos = ((kb * 4 + lq) * 64 + arow) * 8;
                    if (RING) ah[(g4 + 1) & 1][i] = *(const bf16x8*)(hS + apos);
                    else      ah[(g4 + 1) & 1][i] = ld_h16((const unsigned long long*)hS + (apos >> 2));
                }
            }
#pragma unroll
            for (int i = 0; i < 8; ++i) {
                int kb = g4 * 8 + i;
                int bpos = (kb * 64 + l) * 8;
                bf16x8 bh = *(const bf16x8*)&WhHiS[bpos];
                bf16x8 bl = *(const bf16x8*)&WhLoS[bpos];
                bf16x8 a_h = ah[g4 & 1][i];
                acc0 = __builtin_amdgcn_mfma_f32_16x16x32_bf16(a_h, bh, acc0, 0, 0, 0);
                acc2 = __builtin_amdgcn_mfma_f32_16x16x32_bf16(a_h, bl, acc2, 0, 0, 0);
            }
        }

        // z tile -> LDS transpose (stride 20: <=2-way banks, free)
#pragma unroll
        for (int r = 0; r < 4; ++r)
            zS[(w * 16 + lq * 4 + r) * 20 + lc] = acc0[r] + acc2[r];
        __syncthreads();

        float zi = bf2f(gvi) + zS[b_el * 20 + u_el];
        float zf = bf2f(gvf) + zS[b_el * 20 + 4 + u_el];
        float zg = bf2f(gvg) + zS[b_el * 20 + 8 + u_el];
        float zo = bf2f(gvo) + zS[b_el * 20 + 12 + u_el];

        float ig = sigm_fast(zi);
        float fg = sigm_fast(zf);
        float gg = tanh_fast(zg);
        float og = sigm_fast(zo);

        c_state = fg * c_state + ig * gg;
        float nh = og * tanh_fast(c_state);

        if (step == 511) {
            out[(size_t)step * 65536 + b_el * 1024 + j] = nh;
            break;                      // no publish/barrier needed
        }

        // publish h (bf16 hi only, sc1 -> IF$, packed pairs via shfl)
        unsigned int hiw = f2bf(nh);
        unsigned int hi_o = (unsigned int)__shfl_xor((int)hiw, 1);
        if ((t & 1) == 0) {
            int p32 = ((j >> 3) * 64 + b_el) * 4 + ((j & 7) >> 1);
            __hip_atomic_store(nH + p32, (hiw & 0xffffu) | (hi_o << 16),
                               __ATOMIC_RELAXED, __HIP_MEMORY_SCOPE_AGENT);
        }

        // barrier: arrive (publishes drained), deferred out store, poll
        asm volatile("s_waitcnt vmcnt(0)" ::: "memory");
        __syncthreads();
        unsigned int target = (unsigned int)(step + 2);
        if (t == 0)
            __hip_atomic_store(&flags[wg * 32], target, __ATOMIC_RELAXED,
                               __HIP_MEMORY_SCOPE_AGENT);
        out[(size_t)step * 65536 + b_el * 1024 + j] = nh;   // drains next step
        while (__hip_atomic_load(&flags[t * 32], __ATOMIC_RELAXED,
                                 __HIP_MEMORY_SCOPE_AGENT) < target) {}
        __syncthreads();
        asm volatile("" ::: "memory");
    }
}

// ---------------------------------------------------------------------------
extern "C" void kernel_launch(void* const* d_in, const int* in_sizes, int n_in,
                              void* d_out, int out_size, void* d_ws, size_t ws_size,
                              hipStream_t stream)
{
    const float* x  = (const float*)d_in[0];
    const float* h0 = (const float*)d_in[1];
    const float* c0 = (const float*)d_in[2];
    const float* Wi = (const float*)d_in[3];
    const float* Wh = (const float*)d_in[4];
    const float* bb = (const float*)d_in[5];
    float* out = (float*)d_out;

    // ws layout: flags 32KB | WiHi 8MB | WiLo 8MB | G2 256MiB | h slots
    unsigned int* flags = (unsigned int*)d_ws;
    unsigned short* WiHi = (unsigned short*)(flags + 8192);
    unsigned short* WiLo = WiHi + 4194304;
    unsigned short* G2 = WiLo + 4194304;
    unsigned int* hbase = (unsigned int*)(G2 + 134217728);

    const size_t fixed_bytes = 32768ull + 2ull * 8388608ull + 268435456ull;
    const bool ring_ok = ws_size >= fixed_bytes + 513ull * 131072ull;

    hipMemsetAsync(flags, 0, 8192 * sizeof(unsigned int), stream);
    wi_pack<<<dim3(1024), dim3(256), 0, stream>>>(Wi, WiHi, WiLo);
    xwi_gemm_mfma<<<dim3(8192), dim3(256), 0, stream>>>(x, WiHi, WiLo, bb, G2);

    void* args[] = {(void*)&G2, (void*)&Wh, (void*)&h0, (void*)&c0, (void*)&out,
                    (void*)&hbase, (void*)&flags};
    if (ring_ok) {
        hipLaunchCooperativeKernel(reinterpret_cast<void*>(&lstm_scan_mfma<true>),
                                   dim3(256), dim3(256), args, 0, stream);
    } else {
        hipLaunchCooperativeKernel(reinterpret_cast<void*>(&lstm_scan_mfma<false>),
                                   dim3(256), dim3(256), args, 0, stream);
    }
}

// Round 11
// 3496.922 us; speedup vs baseline: 1.3093x; 1.3093x over previous
//
#include <hip/hip_runtime.h>
#include <hip/hip_bf16.h>

// T=512, B=64, D=1024, H=1024, 4H=4096
// Pass 0: pack Wi -> split-bf16 (hi/lo) in MFMA B-fragment order (ws, 16MB)
// Pass 1: G2 = x @ Wi + b via split-bf16 MFMA, scan-native layout:
//         G2[((step*256 + wg)*4 + gate)*256 + b*4 + u]  (bf16)
// Pass 2: cooperative scan, 256 WGs x 4 hidden units, MFMA z = G + h @ Wh.
//         h publish/read: sc1 (IF$-direct), hi-only bf16 (round-9 verified).
//         ROUND-11: global end-of-step barrier dissolved into producer-ranged
//         staged polls inside the K loop (group g needs only WGs 64g..64g+63),
//         overlapped with h loads and MFMA. G2 prefetched one step ahead.

typedef __attribute__((ext_vector_type(8))) short bf16x8;
typedef __attribute__((ext_vector_type(8))) unsigned short ushx8;
typedef __attribute__((ext_vector_type(4))) unsigned short ushx4;
typedef __attribute__((ext_vector_type(4))) float f32x4;
typedef __attribute__((ext_vector_type(2))) unsigned long long u64x2;

static __device__ __forceinline__ unsigned short f2bf(float x) {
    __hip_bfloat16 h = __float2bfloat16(x);
    return __builtin_bit_cast(unsigned short, h);
}
static __device__ __forceinline__ float bf2f(unsigned short u) {
    __hip_bfloat16 h = __builtin_bit_cast(__hip_bfloat16, u);
    return __bfloat162float(h);
}

// coherent (agent-scope, L2-bypassing) 16B load as 2 x u64 relaxed atomics
static __device__ __forceinline__ bf16x8 ld_h16(const unsigned long long* p) {
    unsigned long long a = __hip_atomic_load(p,     __ATOMIC_RELAXED, __HIP_MEMORY_SCOPE_AGENT);
    unsigned long long b = __hip_atomic_load(p + 1, __ATOMIC_RELAXED, __HIP_MEMORY_SCOPE_AGENT);
    u64x2 v; v.x = a; v.y = b;
    return __builtin_bit_cast(bf16x8, v);
}

static __device__ __forceinline__ void gl_lds16(const void* g, void* l) {
    __builtin_amdgcn_global_load_lds(
        (const __attribute__((address_space(1))) unsigned int*)g,
        (__attribute__((address_space(3))) unsigned int*)l, 16, 0, 0);
}

static __device__ __forceinline__ float sigm_fast(float x) {
    return 1.f / (1.f + __expf(-x));
}
static __device__ __forceinline__ float tanh_fast(float x) {
    float e = __expf(2.f * x);
    return 1.f - 2.f / (e + 1.f);
}

// ---------------------------------------------------------------------------
// Pass 0: pack Wi[1024][4096] f32 -> WiHi/WiLo bf16 in B-fragment order.
// ---------------------------------------------------------------------------
__global__ __launch_bounds__(256)
void wi_pack(const float* __restrict__ Wi, unsigned short* __restrict__ WiHi,
             unsigned short* __restrict__ WiLo)
{
    const int bid = blockIdx.x;            // 1024 = tn(32) x kb(32)
    const int tn = bid >> 5, kb = bid & 31;
    const int t = threadIdx.x;
    const int c = t & 127, ko = t >> 7;
    const float* src = Wi + (size_t)(kb * 32 + ko * 16) * 4096 + tn * 128 + c;
    const size_t dbase = ((size_t)(tn * 32 + kb)) * 4096 + c * 8;
#pragma unroll
    for (int o = 0; o < 2; ++o) {
        ushx8 hv, lv;
#pragma unroll
        for (int q = 0; q < 8; ++q) {
            float v = src[(size_t)(o * 8 + q) * 4096];
            unsigned short h = f2bf(v);
            hv[q] = h; lv[q] = f2bf(v - bf2f(h));
        }
        int kq = ko * 2 + o;
        *(ushx8*)(WiHi + dbase + kq * 1024) = hv;
        *(ushx8*)(WiLo + dbase + kq * 1024) = lv;
    }
}

// ---------------------------------------------------------------------------
// Pass 1: G2 = x @ Wi + bias, split-bf16 MFMA, 128x128 tile, BK=32, 4 waves.
// ---------------------------------------------------------------------------
__global__ __launch_bounds__(256)
void xwi_gemm_mfma(const float* __restrict__ x,
                   const unsigned short* __restrict__ WiHi,
                   const unsigned short* __restrict__ WiLo,
                   const float* __restrict__ bias,
                   unsigned short* __restrict__ G2)
{
    __shared__ __align__(16) unsigned short AHi[4096], ALo[4096];
    __shared__ __align__(16) unsigned short BHi[4096], BLo[4096];
    const int bid = blockIdx.x;
    const int bm = bid >> 5, bn = bid & 31;
    const int m0 = bm << 7, n0 = bn << 7;
    const int t = threadIdx.x;
    const int w = t >> 6, l = t & 63, lq = l >> 4, lc = l & 15;
    const int wm = w >> 1, wn = w & 1;

    f32x4 acc[4][4] = {};
    const int row = t >> 1, kh = t & 1;
    const float* xrow = x + (size_t)(m0 + row) * 1024 + kh * 16;
    const unsigned short* bHsl = WiHi + (size_t)(bn * 32) * 4096;
    const unsigned short* bLsl = WiLo + (size_t)(bn * 32) * 4096;

    for (int kb = 0; kb < 32; ++kb) {
        float4 f0 = *(const float4*)(xrow + kb * 32 + 0);
        float4 f1 = *(const float4*)(xrow + kb * 32 + 4);
        float4 f2 = *(const float4*)(xrow + kb * 32 + 8);
        float4 f3 = *(const float4*)(xrow + kb * 32 + 12);
        float fs[16] = {f0.x, f0.y, f0.z, f0.w, f1.x, f1.y, f1.z, f1.w,
                        f2.x, f2.y, f2.z, f2.w, f3.x, f3.y, f3.z, f3.w};
#pragma unroll
        for (int o = 0; o < 2; ++o) {
            ushx8 hv, lv;
#pragma unroll
            for (int q = 0; q < 8; ++q) {
                float v = fs[o * 8 + q];
                unsigned short h = f2bf(v);
                hv[q] = h; lv[q] = f2bf(v - bf2f(h));
            }
            int kq = kh * 2 + o;
            *(ushx8*)&AHi[kq * 1024 + row * 8] = hv;
            *(ushx8*)&ALo[kq * 1024 + row * 8] = lv;
        }
        {
            const unsigned short* sH = bHsl + (size_t)kb * 4096;
            const unsigned short* sL = bLsl + (size_t)kb * 4096;
            gl_lds16(sH + (size_t)(w * 128 + l) * 8,      &BHi[(w * 128) * 8]);
            gl_lds16(sH + (size_t)(w * 128 + 64 + l) * 8, &BHi[(w * 128 + 64) * 8]);
            gl_lds16(sL + (size_t)(w * 128 + l) * 8,      &BLo[(w * 128) * 8]);
            gl_lds16(sL + (size_t)(w * 128 + 64 + l) * 8, &BLo[(w * 128 + 64) * 8]);
        }
        __syncthreads();

        bf16x8 xh[4], xl[4], wh_[4], wl_[4];
#pragma unroll
        for (int a = 0; a < 4; ++a) {
            int off = lq * 1024 + (wm * 64 + a * 16 + lc) * 8;
            xh[a] = *(const bf16x8*)&AHi[off];
            xl[a] = *(const bf16x8*)&ALo[off];
        }
#pragma unroll
        for (int b = 0; b < 4; ++b) {
            int off = lq * 1024 + (wn * 64 + b * 16 + lc) * 8;
            wh_[b] = *(const bf16x8*)&BHi[off];
            wl_[b] = *(const bf16x8*)&BLo[off];
        }
#pragma unroll
        for (int a = 0; a < 4; ++a)
#pragma unroll
            for (int b = 0; b < 4; ++b) {
                acc[a][b] = __builtin_amdgcn_mfma_f32_16x16x32_bf16(wh_[b], xh[a], acc[a][b], 0, 0, 0);
                acc[a][b] = __builtin_amdgcn_mfma_f32_16x16x32_bf16(wl_[b], xh[a], acc[a][b], 0, 0, 0);
                acc[a][b] = __builtin_amdgcn_mfma_f32_16x16x32_bf16(wh_[b], xl[a], acc[a][b], 0, 0, 0);
            }
        __syncthreads();
    }

    float bv[4][4];
#pragma unroll
    for (int b = 0; b < 4; ++b)
#pragma unroll
        for (int r = 0; r < 4; ++r)
            bv[b][r] = bias[n0 + wn * 64 + b * 16 + lq * 4 + r];
#pragma unroll
    for (int a = 0; a < 4; ++a) {
        int m = m0 + wm * 64 + a * 16 + lc;
        int step = m >> 6, b_el = m & 63;
#pragma unroll
        for (int b = 0; b < 4; ++b) {
            int j_abs = n0 + wn * 64 + b * 16 + lq * 4;
            int gate = j_abs >> 10;
            int wg_t = (j_abs & 1023) >> 2;
            ushx4 sv;
#pragma unroll
            for (int r = 0; r < 4; ++r) sv[r] = f2bf(acc[a][b][r] + bv[b][r]);
            *(ushx4*)(G2 + (((size_t)(step * 256 + wg_t) * 4 + gate) * 256 + b_el * 4)) = sv;
        }
    }
}

// ---------------------------------------------------------------------------
// Pass 2: cooperative MFMA scan, staged producer-ranged polls.
// ---------------------------------------------------------------------------
__global__ __launch_bounds__(256, 1)
void lstm_scan_mfma(const unsigned short* __restrict__ G2,
                    const float* __restrict__ Wh,
                    const float* __restrict__ h0, const float* __restrict__ c0,
                    float* __restrict__ out,
                    unsigned int* __restrict__ hp0,
                    unsigned int* __restrict__ hp1,
                    unsigned int* __restrict__ flags)
{
    __shared__ __align__(16) unsigned short WhHiS[16384];  // 32 KB
    __shared__ __align__(16) unsigned short WhLoS[16384];  // 32 KB
    __shared__ float zS[64 * 20];

    const int t  = threadIdx.x;
    const int wg = blockIdx.x;           // 0..255
    const int w  = t >> 6;
    const int l  = t & 63;
    const int lq = l >> 4, lc = l & 15;

    // Wh slice -> LDS (once): 16 z-cols, hi/lo split, B-fragment order
    for (int idx = t; idx < 16384; idx += 256) {
        int k = idx >> 4, c = idx & 15;
        int gcol = (c >> 2) * 1024 + wg * 4 + (c & 3);
        float wv = Wh[(size_t)k * 4096 + gcol];
        unsigned short hi = f2bf(wv);
        unsigned short lo = f2bf(wv - bf2f(hi));
        int pos = (((k >> 5) * 64) + (((k >> 3) & 3) * 16 + c)) * 8 + (k & 7);
        WhHiS[pos] = hi; WhLoS[pos] = lo;
    }

    // init hp0 from h0 (bf16 hi only, sc1 -> IF$)
    {
        int idx = wg * 256 + t;
        if (idx < 32768) {
            int b = idx >> 9, k = (idx & 511) * 2;
            unsigned short h0s = f2bf(h0[b * 1024 + k]);
            unsigned short h1s = f2bf(h0[b * 1024 + k + 1]);
            int p32 = ((k >> 3) * 64 + b) * 4 + ((k & 7) >> 1);
            __hip_atomic_store(hp0 + p32, (unsigned int)h0s | ((unsigned int)h1s << 16),
                               __ATOMIC_RELAXED, __HIP_MEMORY_SCOPE_AGENT);
        }
    }

    const int b_el = t >> 2, u_el = t & 3;
    const int j = wg * 4 + u_el;
    float c_state = c0[b_el * 1024 + j];

    // initial barrier (round-5 form, full poll)
    {
        asm volatile("s_waitcnt vmcnt(0)" ::: "memory");
        __syncthreads();
        if (t == 0)
            __hip_atomic_store(&flags[wg * 32], 1u, __ATOMIC_RELAXED,
                               __HIP_MEMORY_SCOPE_AGENT);
        while (__hip_atomic_load(&flags[t * 32], __ATOMIC_RELAXED,
                                 __HIP_MEMORY_SCOPE_AGENT) < 1u) {}
        __syncthreads();
        asm volatile("" ::: "memory");
    }

    const int arow = (w << 4) + lc;

    // G2 prefetch for step 0 (G2 fully written before this kernel launched)
    unsigned short gvi, gvf, gvg, gvo;
    {
        size_t pb = ((size_t)(0 * 256 + wg) * 4) * 256 + t;
        gvi = G2[pb]; gvf = G2[pb + 256]; gvg = G2[pb + 512]; gvo = G2[pb + 768];
    }

#define POLL_GRP(G, TGT)                                                        \
    {                                                                           \
        const unsigned int* fp = flags + ((G) * 64 + l) * 32;                   \
        while (__hip_atomic_load(fp, __ATOMIC_RELAXED,                          \
                                 __HIP_MEMORY_SCOPE_AGENT) < (TGT)) {}          \
        asm volatile("" ::: "memory");                                          \
    }

#define LOAD_GRP(DST, G)                                                        \
    _Pragma("unroll") for (int i = 0; i < 8; ++i) {                             \
        int a64 = ((((G) * 8 + i) * 4 + lq) * 64 + arow) * 2;                   \
        DST[i] = ld_h16(hH + a64);                                              \
    }

#define MFMA_GRP(SRC, G)                                                        \
    _Pragma("unroll") for (int i = 0; i < 8; ++i) {                             \
        int bpos = ((((G) * 8 + i)) * 64 + l) * 8;                              \
        bf16x8 bh = *(const bf16x8*)&WhHiS[bpos];                               \
        bf16x8 bl = *(const bf16x8*)&WhLoS[bpos];                               \
        acc0 = __builtin_amdgcn_mfma_f32_16x16x32_bf16(SRC[i], bh, acc0, 0, 0, 0); \
        acc2 = __builtin_amdgcn_mfma_f32_16x16x32_bf16(SRC[i], bl, acc2, 0, 0, 0); \
    }

    for (int step = 0; step < 512; ++step) {
        const unsigned long long* hH =
            (const unsigned long long*)((step & 1) ? hp1 : hp0);
        unsigned int* nH = (step & 1) ? hp0 : hp1;
        const unsigned int rt = (unsigned int)(step + 1);

        f32x4 acc0 = {0.f, 0.f, 0.f, 0.f};
        f32x4 acc2 = {0.f, 0.f, 0.f, 0.f};

        bf16x8 ahA[8], ahB[8];
        POLL_GRP(0, rt)
        LOAD_GRP(ahA, 0)
        POLL_GRP(1, rt)
        LOAD_GRP(ahB, 1)
        MFMA_GRP(ahA, 0)
        POLL_GRP(2, rt)
        LOAD_GRP(ahA, 2)
        MFMA_GRP(ahB, 1)
        POLL_GRP(3, rt)
        LOAD_GRP(ahB, 3)
        MFMA_GRP(ahA, 2)

        // prefetch G2 for next step (in flight across arrive + next polls)
        unsigned short gvin, gvfn, gvgn, gvon;
        {
            int pstep = (step < 511) ? step + 1 : 511;
            size_t pbn = ((size_t)(pstep * 256 + wg) * 4) * 256 + t;
            gvin = G2[pbn]; gvfn = G2[pbn + 256];
            gvgn = G2[pbn + 512]; gvon = G2[pbn + 768];
        }

        MFMA_GRP(ahB, 3)

        // z tile -> LDS transpose (stride 20: <=2-way banks, free)
#pragma unroll
        for (int r = 0; r < 4; ++r)
            zS[(w * 16 + lq * 4 + r) * 20 + lc] = acc0[r] + acc2[r];
        __syncthreads();

        float zi = bf2f(gvi) + zS[b_el * 20 + u_el];
        float zf = bf2f(gvf) + zS[b_el * 20 + 4 + u_el];
        float zg = bf2f(gvg) + zS[b_el * 20 + 8 + u_el];
        float zo = bf2f(gvo) + zS[b_el * 20 + 12 + u_el];

        gvi = gvin; gvf = gvfn; gvg = gvgn; gvo = gvon;

        float ig = sigm_fast(zi);
        float fg = sigm_fast(zf);
        float gg = tanh_fast(zg);
        float og = sigm_fast(zo);

        c_state = fg * c_state + ig * gg;
        float nh = og * tanh_fast(c_state);

        if (step == 511) {
            out[(size_t)step * 65536 + b_el * 1024 + j] = nh;
            break;                      // no publish/arrive needed
        }

        // publish h (bf16 hi only, sc1 -> IF$, packed pairs via shfl)
        unsigned int hiw = f2bf(nh);
        unsigned int hi_o = (unsigned int)__shfl_xor((int)hiw, 1);
        if ((t & 1) == 0) {
            int p32 = ((j >> 3) * 64 + b_el) * 4 + ((j & 7) >> 1);
            __hip_atomic_store(nH + p32, (hiw & 0xffffu) | (hi_o << 16),
                               __ATOMIC_RELAXED, __HIP_MEMORY_SCOPE_AGENT);
        }

        // arrive only (no end poll — next step's staged polls take over):
        // drain publishes, sync waves (also closes zS read window), set flag,
        // then the deferred out store drains under next step's first poll.
        asm volatile("s_waitcnt vmcnt(0)" ::: "memory");
        __syncthreads();
        if (t == 0)
            __hip_atomic_store(&flags[wg * 32], (unsigned int)(step + 2),
                               __ATOMIC_RELAXED, __HIP_MEMORY_SCOPE_AGENT);
        out[(size_t)step * 65536 + b_el * 1024 + j] = nh;
    }

#undef POLL_GRP
#undef LOAD_GRP
#undef MFMA_GRP
}

// ---------------------------------------------------------------------------
extern "C" void kernel_launch(void* const* d_in, const int* in_sizes, int n_in,
                              void* d_out, int out_size, void* d_ws, size_t ws_size,
                              hipStream_t stream)
{
    const float* x  = (const float*)d_in[0];
    const float* h0 = (const float*)d_in[1];
    const float* c0 = (const float*)d_in[2];
    const float* Wi = (const float*)d_in[3];
    const float* Wh = (const float*)d_in[4];
    const float* bb = (const float*)d_in[5];
    float* out = (float*)d_out;

    // ws layout: hp0/hp1 (128KB each) | flags 32KB | WiHi 8MB | WiLo 8MB | G2 268MB
    unsigned int* hp0 = (unsigned int*)d_ws;
    unsigned int* hp1 = hp0 + 32768;
    unsigned int* flags = hp1 + 32768;          // 256 * 32 u32 = 32KB
    unsigned short* WiHi = (unsigned short*)(flags + 8192);
    unsigned short* WiLo = WiHi + 4194304;
    unsigned short* G2 = WiLo + 4194304;

    hipMemsetAsync(flags, 0, 8192 * sizeof(unsigned int), stream);
    wi_pack<<<dim3(1024), dim3(256), 0, stream>>>(Wi, WiHi, WiLo);
    xwi_gemm_mfma<<<dim3(8192), dim3(256), 0, stream>>>(x, WiHi, WiLo, bb, G2);

    void* args[] = {(void*)&G2, (void*)&Wh, (void*)&h0, (void*)&c0, (void*)&out,
                    (void*)&hp0, (void*)&hp1, (void*)&flags};
    hipLaunchCooperativeKernel(reinterpret_cast<void*>(&lstm_scan_mfma),
                               dim3(256), dim3(256), args, 0, stream);
}